// Round 1
// baseline (992.644 us; speedup 1.0000x reference)
//
#include <hip/hip_runtime.h>
#include <hip/hip_bf16.h>

typedef __bf16 bf16_t;
typedef bf16_t bf16x4 __attribute__((ext_vector_type(4)));
typedef bf16_t bf16x8 __attribute__((ext_vector_type(8)));
typedef float f32x4 __attribute__((ext_vector_type(4)));

static constexpr int N_NODES = 50000;
static constexpr int N_EDGES = 1600000;
static constexpr int FIN = 1280;
static constexpr int HD = 128;
static constexpr int NG = 64;
// 0.5/sqrt(pi)/sqrt(128)
static constexpr float TP_NORM_F = 0.0249338908f;

// ---- transpose + scale + cast: src [K x 128] f32 -> dst [128 x K] bf16
__global__ __launch_bounds__(256) void k_transpose_scale(const float* __restrict__ src,
                                                         bf16_t* __restrict__ dst,
                                                         int K, float scale) {
  int idx = blockIdx.x * 256 + threadIdx.x;
  if (idx >= K * HD) return;
  int k = idx >> 7, n = idx & 127;
  dst[n * K + k] = (bf16_t)(src[idx] * scale);
}

// ---- MFMA GEMM: C[M x 128] = act(A[M x K] @ Bt^T + bias), A f32, Bt bf16 [128 x K]
// 128x128 block tile, 4 waves of 64x64, BK=64, XOR-swizzled LDS (conflict-free b128).
__global__ __launch_bounds__(256) void k_gemm(const float* __restrict__ A,
                                              const bf16_t* __restrict__ Bt,
                                              const float* __restrict__ bias,
                                              bf16_t* __restrict__ C,
                                              int M, int K, int doRelu) {
  __shared__ bf16_t As[128 * 64];
  __shared__ bf16_t Bs[128 * 64];
  const int t = threadIdx.x;
  const int wid = t >> 6;
  const int lane = t & 63;
  const int wm = (wid & 1) * 64;
  const int wn = (wid >> 1) * 64;
  const int l15 = lane & 15;
  const int quad = lane >> 4;
  const int rowBase = blockIdx.x * 128;

  f32x4 acc[4][4];
#pragma unroll
  for (int i = 0; i < 4; ++i)
#pragma unroll
    for (int j = 0; j < 4; ++j) {
      f32x4 z = {0.f, 0.f, 0.f, 0.f};
      acc[i][j] = z;
    }

  for (int k0 = 0; k0 < K; k0 += 64) {
    // stage A: 128 rows x 64 cols, f32 -> bf16, swizzled at 16B-chunk granularity
#pragma unroll
    for (int i = 0; i < 8; ++i) {
      int idx = t + i * 256;
      int row = idx >> 4;   // 0..127
      int col4 = idx & 15;  // float4 units
      int gr = rowBase + row;
      float4 v = make_float4(0.f, 0.f, 0.f, 0.f);
      if (gr < M) v = *(const float4*)(A + (size_t)gr * K + k0 + col4 * 4);
      bf16x4 w;
      w[0] = (bf16_t)v.x; w[1] = (bf16_t)v.y; w[2] = (bf16_t)v.z; w[3] = (bf16_t)v.w;
      int c = col4 >> 1;
      int off = row * 64 + ((c ^ (row & 7)) << 3) + ((col4 & 1) << 2);
      *(bf16x4*)&As[off] = w;
    }
    // stage B: 128 rows x 64 cols bf16, 16B chunks, swizzled
#pragma unroll
    for (int i = 0; i < 4; ++i) {
      int idx = t + i * 256;
      int row = idx >> 3;  // 0..127
      int c = idx & 7;     // 16B chunk
      bf16x8 v = *(const bf16x8*)(Bt + (size_t)row * K + k0 + c * 8);
      int off = row * 64 + ((c ^ (row & 7)) << 3);
      *(bf16x8*)&Bs[off] = v;
    }
    __syncthreads();
#pragma unroll
    for (int kk = 0; kk < 2; ++kk) {
      bf16x8 af[4], bfr[4];
#pragma unroll
      for (int mi = 0; mi < 4; ++mi) {
        int row = wm + mi * 16 + l15;
        int k8 = kk * 4 + quad;
        af[mi] = *(const bf16x8*)&As[row * 64 + ((k8 ^ (row & 7)) << 3)];
      }
#pragma unroll
      for (int ni = 0; ni < 4; ++ni) {
        int row = wn + ni * 16 + l15;
        int k8 = kk * 4 + quad;
        bfr[ni] = *(const bf16x8*)&Bs[row * 64 + ((k8 ^ (row & 7)) << 3)];
      }
#pragma unroll
      for (int mi = 0; mi < 4; ++mi)
#pragma unroll
        for (int ni = 0; ni < 4; ++ni)
          acc[mi][ni] = __builtin_amdgcn_mfma_f32_16x16x32_bf16(af[mi], bfr[ni], acc[mi][ni], 0, 0, 0);
    }
    __syncthreads();
  }

  // epilogue: C/D layout col=lane&15, row=quad*4+reg  (m89-verified)
#pragma unroll
  for (int mi = 0; mi < 4; ++mi) {
#pragma unroll
    for (int ni = 0; ni < 4; ++ni) {
      int col = wn + ni * 16 + l15;
      float bv = bias ? bias[col] : 0.f;
#pragma unroll
      for (int r = 0; r < 4; ++r) {
        int row = wm + mi * 16 + quad * 4 + r;
        int gr = rowBase + row;
        if (gr < M) {
          float v = acc[mi][ni][r] + bv;
          if (doRelu) v = fmaxf(v, 0.f);
          C[(size_t)gr * HD + col] = (bf16_t)v;
        }
      }
    }
  }
}

// ---- CSR build
__global__ __launch_bounds__(256) void k_count(const int* __restrict__ dst, int* __restrict__ cnt, int E) {
  int e = blockIdx.x * 256 + threadIdx.x;
  if (e < E) atomicAdd(&cnt[dst[e]], 1);
}

__global__ __launch_bounds__(1024) void k_scan(const int* __restrict__ cnt, int* __restrict__ off, int n) {
  __shared__ int s[1024];
  int t = threadIdx.x;
  int running = 0;
  for (int base = 0; base < n; base += 1024) {
    int i = base + t;
    int v = (i < n) ? cnt[i] : 0;
    s[t] = v;
    __syncthreads();
    for (int d = 1; d < 1024; d <<= 1) {
      int x = (t >= d) ? s[t - d] : 0;
      __syncthreads();
      s[t] += x;
      __syncthreads();
    }
    int incl = s[t];
    if (i < n) off[i] = running + incl - v;
    running += s[1023];
    __syncthreads();
  }
  if (t == 0) off[n] = running;
}

__global__ __launch_bounds__(256) void k_fill(const int* __restrict__ src, const int* __restrict__ dst,
                                              const int* __restrict__ off, int* __restrict__ cur,
                                              int* __restrict__ ssrc, int E) {
  int e = blockIdx.x * 256 + threadIdx.x;
  if (e >= E) return;
  int d = dst[e];
  int pos = atomicAdd(&cur[d], 1);
  ssrc[off[d] + pos] = src[e];
}

// ---- CSR mean-aggregate: agg[node] = mean over in-edges of h[src], 16 lanes/node x 8 feats
__global__ __launch_bounds__(256) void k_aggregate(const bf16_t* __restrict__ h,
                                                   const int* __restrict__ ssrc,
                                                   const int* __restrict__ off,
                                                   float* __restrict__ agg, int n) {
  int node = blockIdx.x * 16 + (threadIdx.x >> 4);
  int lane = threadIdx.x & 15;
  if (node >= n) return;
  int b = off[node], e = off[node + 1];
  float acc[8];
#pragma unroll
  for (int j = 0; j < 8; ++j) acc[j] = 0.f;
  const bf16_t* hp = h + lane * 8;
  int i = b;
  for (; i + 2 <= e; i += 2) {
    int s0 = ssrc[i], s1 = ssrc[i + 1];
    bf16x8 v0 = *(const bf16x8*)(hp + (size_t)s0 * HD);
    bf16x8 v1 = *(const bf16x8*)(hp + (size_t)s1 * HD);
#pragma unroll
    for (int j = 0; j < 8; ++j) acc[j] += (float)v0[j] + (float)v1[j];
  }
  if (i < e) {
    int s0 = ssrc[i];
    bf16x8 v0 = *(const bf16x8*)(hp + (size_t)s0 * HD);
#pragma unroll
    for (int j = 0; j < 8; ++j) acc[j] += (float)v0[j];
  }
  float inv = (e > b) ? 1.f / (float)(e - b) : 0.f;
  float* op = agg + (size_t)node * HD + lane * 8;
  float4 o0 = make_float4(acc[0] * inv, acc[1] * inv, acc[2] * inv, acc[3] * inv);
  float4 o1 = make_float4(acc[4] * inv, acc[5] * inv, acc[6] * inv, acc[7] * inv);
  *(float4*)op = o0;
  *(float4*)(op + 4) = o1;
}

// ---- pool: segment-sum agg over sorted batch into p[64x128] + counts
__global__ __launch_bounds__(128) void k_pool(const float* __restrict__ agg, const int* __restrict__ batch,
                                              float* __restrict__ p, float* __restrict__ gcnt, int n) {
  int base = blockIdx.x * 256;
  if (base >= n) return;
  int t = threadIdx.x;
  int end = min(base + 256, n);
  float acc = 0.f;
  int curg = batch[base];
  int runStart = base;
  for (int i = base; i < end; ++i) {
    int g = batch[i];
    if (g != curg) {
      atomicAdd(&p[curg * HD + t], acc);
      if (t == 0) atomicAdd(&gcnt[curg], (float)(i - runStart));
      acc = 0.f; curg = g; runStart = i;
    }
    acc += agg[(size_t)i * HD + t];
  }
  atomicAdd(&p[curg * HD + t], acc);
  if (t == 0) atomicAdd(&gcnt[curg], (float)(end - runStart));
}

// ---- head: z = (p/cnt) @ (w3*norm); out = mlp(z). One block per graph.
__global__ __launch_bounds__(128) void k_head(const float* __restrict__ p, const float* __restrict__ gcnt,
                                              const float* __restrict__ w3,
                                              const float* __restrict__ c1w, const float* __restrict__ c1b,
                                              const float* __restrict__ c2w, const float* __restrict__ c2b,
                                              const float* __restrict__ c3w, const float* __restrict__ c3b,
                                              float* __restrict__ out) {
  __shared__ float sa[128], sb[128];
  int g = blockIdx.x, t = threadIdx.x;
  float inv = 1.f / fmaxf(gcnt[g], 1.f);
  sa[t] = p[g * HD + t] * inv;
  __syncthreads();
  float z = 0.f;
  for (int k = 0; k < HD; ++k) z += sa[k] * w3[k * HD + t];
  z *= TP_NORM_F;
  out[128 + g * HD + t] = z;  // second output (z) region
  sb[t] = z;
  __syncthreads();
  float o1 = c1b[t];
  for (int k = 0; k < HD; ++k) o1 += sb[k] * c1w[k * HD + t];
  o1 = fmaxf(o1, 0.f);
  __syncthreads();
  sa[t] = o1;
  __syncthreads();
  float o2 = c2b[t];
  for (int k = 0; k < HD; ++k) o2 += sa[k] * c2w[k * HD + t];
  o2 = fmaxf(o2, 0.f);
  __syncthreads();
  sb[t] = o2;
  __syncthreads();
  if (t < 2) {
    float o = c3b[t];
    for (int k = 0; k < HD; ++k) o += sb[k] * c3w[k * 2 + t];
    out[g * 2 + t] = o;  // first output region
  }
}

extern "C" void kernel_launch(void* const* d_in, const int* in_sizes, int n_in,
                              void* d_out, int out_size, void* d_ws, size_t ws_size,
                              hipStream_t stream) {
  const float* x = (const float*)d_in[0];
  const int* eidx = (const int*)d_in[2];
  const int* src = eidx;
  const int* dst = eidx + N_EDGES;
  const int* batch = (const int*)d_in[3];
  const float* lin_w = (const float*)d_in[4];
  const float* lin_b = (const float*)d_in[5];
  const float* tp_w1 = (const float*)d_in[6];
  const float* tp_w2 = (const float*)d_in[7];
  const float* tp_w3 = (const float*)d_in[8];
  const float* c1w = (const float*)d_in[9];
  const float* c1b = (const float*)d_in[10];
  const float* c2w = (const float*)d_in[11];
  const float* c2b = (const float*)d_in[12];
  const float* c3w = (const float*)d_in[13];
  const float* c3b = (const float*)d_in[14];
  float* out = (float*)d_out;
  (void)in_sizes; (void)n_in; (void)out_size; (void)ws_size;

  uintptr_t wp = (uintptr_t)d_ws;
  auto alloc = [&](size_t bytes) -> void* {
    uintptr_t a = (wp + 255) & ~(uintptr_t)255;
    wp = a + bytes;
    return (void*)a;
  };
  bf16_t* WtL  = (bf16_t*)alloc(sizeof(bf16_t) * (size_t)HD * FIN);
  bf16_t* Wt1  = (bf16_t*)alloc(sizeof(bf16_t) * (size_t)HD * HD);
  bf16_t* Wt2  = (bf16_t*)alloc(sizeof(bf16_t) * (size_t)HD * HD);
  bf16_t* h    = (bf16_t*)alloc(sizeof(bf16_t) * (size_t)50048 * HD);
  float*  agg  = (float*)alloc(sizeof(float) * (size_t)N_NODES * HD);
  int*    cnt  = (int*)alloc(sizeof(int) * N_NODES);
  int*    offs = (int*)alloc(sizeof(int) * (N_NODES + 1));
  int*    curp = (int*)alloc(sizeof(int) * N_NODES);
  int*    ssrc = (int*)alloc(sizeof(int) * N_EDGES);
  float*  pbuf = (float*)alloc(sizeof(float) * NG * HD);
  float*  gcnt = (float*)alloc(sizeof(float) * NG);

  hipMemsetAsync(cnt, 0, sizeof(int) * N_NODES, stream);
  hipMemsetAsync(curp, 0, sizeof(int) * N_NODES, stream);
  hipMemsetAsync(pbuf, 0, sizeof(float) * NG * HD, stream);
  hipMemsetAsync(gcnt, 0, sizeof(float) * NG, stream);

  k_transpose_scale<<<(FIN * HD + 255) / 256, 256, 0, stream>>>(lin_w, WtL, FIN, 1.0f);
  k_transpose_scale<<<(HD * HD + 255) / 256, 256, 0, stream>>>(tp_w1, Wt1, HD, TP_NORM_F);
  k_transpose_scale<<<(HD * HD + 255) / 256, 256, 0, stream>>>(tp_w2, Wt2, HD, TP_NORM_F);

  k_count<<<(N_EDGES + 255) / 256, 256, 0, stream>>>(dst, cnt, N_EDGES);
  k_scan<<<1, 1024, 0, stream>>>(cnt, offs, N_NODES);
  k_fill<<<(N_EDGES + 255) / 256, 256, 0, stream>>>(src, dst, offs, curp, ssrc, N_EDGES);

  const int gblocks = (N_NODES + 127) / 128;  // 391
  const int ablocks = (N_NODES + 15) / 16;    // 3125

  // h0 = relu(x @ lin_w + b)
  k_gemm<<<gblocks, 256, 0, stream>>>(x, WtL, lin_b, h, N_NODES, FIN, 1);

  // conv1: agg = mean_agg(h0[src]); h1 = relu(agg @ W1*norm)
  k_aggregate<<<ablocks, 256, 0, stream>>>(h, ssrc, offs, agg, N_NODES);
  k_gemm<<<gblocks, 256, 0, stream>>>(agg, Wt1, nullptr, h, N_NODES, HD, 1);
  // conv2
  k_aggregate<<<ablocks, 256, 0, stream>>>(h, ssrc, offs, agg, N_NODES);
  k_gemm<<<gblocks, 256, 0, stream>>>(agg, Wt2, nullptr, h, N_NODES, HD, 1);
  // conv3 aggregation only (W3 folded into head via linearity of segment-mean)
  k_aggregate<<<ablocks, 256, 0, stream>>>(h, ssrc, offs, agg, N_NODES);

  k_pool<<<(N_NODES + 255) / 256, 128, 0, stream>>>(agg, batch, pbuf, gcnt, N_NODES);
  k_head<<<NG, 128, 0, stream>>>(pbuf, gcnt, tp_w3, c1w, c1b, c2w, c2b, c3w, c3b, out);
}

// Round 2
// 878.208 us; speedup vs baseline: 1.1303x; 1.1303x over previous
//
#include <hip/hip_runtime.h>
#include <hip/hip_bf16.h>

typedef __bf16 bf16_t;
typedef bf16_t bf16x4 __attribute__((ext_vector_type(4)));
typedef bf16_t bf16x8 __attribute__((ext_vector_type(8)));
typedef float f32x4 __attribute__((ext_vector_type(4)));

static constexpr int N_NODES = 50000;
static constexpr int N_EDGES = 1600000;
static constexpr int FIN = 1280;
static constexpr int HD = 128;
static constexpr int NG = 64;
// 0.5/sqrt(pi)/sqrt(128)
static constexpr float TP_NORM_F = 0.0249338908f;

// ---- transpose + scale + cast: src [K x 128] f32 -> dst [128 x K] bf16
__global__ __launch_bounds__(256) void k_transpose_scale(const float* __restrict__ src,
                                                         bf16_t* __restrict__ dst,
                                                         int K, float scale) {
  int idx = blockIdx.x * 256 + threadIdx.x;
  if (idx >= K * HD) return;
  int k = idx >> 7, n = idx & 127;
  dst[n * K + k] = (bf16_t)(src[idx] * scale);
}

// ---- MFMA GEMM: C[M x 128] = act(A[M x K] @ Bt^T + bias)
// 64x128 block tile (782 blocks -> ~3 blocks/CU), 4 waves of 32x64, BK=64,
// XOR-swizzled LDS. AT = float (cvt during staging) or bf16 (direct copy).
template <typename AT>
__global__ __launch_bounds__(256) void k_gemm64(const AT* __restrict__ A,
                                                const bf16_t* __restrict__ Bt,
                                                const float* __restrict__ bias,
                                                bf16_t* __restrict__ C,
                                                int M, int K, int doRelu) {
  __shared__ bf16_t As[64 * 64];
  __shared__ bf16_t Bs[128 * 64];
  const int t = threadIdx.x;
  const int wid = t >> 6;
  const int lane = t & 63;
  const int wm = (wid & 1) * 32;
  const int wn = (wid >> 1) * 64;
  const int l15 = lane & 15;
  const int quad = lane >> 4;
  const int rowBase = blockIdx.x * 64;

  f32x4 acc[2][4];
#pragma unroll
  for (int i = 0; i < 2; ++i)
#pragma unroll
    for (int j = 0; j < 4; ++j) {
      f32x4 z = {0.f, 0.f, 0.f, 0.f};
      acc[i][j] = z;
    }

  for (int k0 = 0; k0 < K; k0 += 64) {
    if constexpr (sizeof(AT) == 4) {
      // A: 64 rows x 64 f32 cols -> bf16, 1024 float4 chunks / 256 thr = 4 each
#pragma unroll
      for (int i = 0; i < 4; ++i) {
        int idx = t + i * 256;
        int row = idx >> 4;   // 0..63
        int col4 = idx & 15;  // float4 units
        int gr = rowBase + row;
        float4 v = make_float4(0.f, 0.f, 0.f, 0.f);
        if (gr < M) v = *(const float4*)(A + (size_t)gr * K + k0 + col4 * 4);
        bf16x4 w;
        w[0] = (bf16_t)v.x; w[1] = (bf16_t)v.y; w[2] = (bf16_t)v.z; w[3] = (bf16_t)v.w;
        int c = col4 >> 1;
        int off = row * 64 + ((c ^ (row & 7)) << 3) + ((col4 & 1) << 2);
        *(bf16x4*)&As[off] = w;
      }
    } else {
      // A: 64 rows x 64 bf16 cols, 512 bf16x8 chunks / 256 thr = 2 each
#pragma unroll
      for (int i = 0; i < 2; ++i) {
        int idx = t + i * 256;
        int row = idx >> 3;  // 0..63
        int c = idx & 7;     // 16B chunk
        int gr = rowBase + row;
        bf16x8 v = {};
        if (gr < M) v = *(const bf16x8*)(A + (size_t)gr * K + k0 + c * 8);
        int off = row * 64 + ((c ^ (row & 7)) << 3);
        *(bf16x8*)&As[off] = v;
      }
    }
    // B: 128 rows x 64 bf16 cols, 1024 chunks / 256 thr = 4 each
#pragma unroll
    for (int i = 0; i < 4; ++i) {
      int idx = t + i * 256;
      int row = idx >> 3;  // 0..127
      int c = idx & 7;
      bf16x8 v = *(const bf16x8*)(Bt + (size_t)row * K + k0 + c * 8);
      int off = row * 64 + ((c ^ (row & 7)) << 3);
      *(bf16x8*)&Bs[off] = v;
    }
    __syncthreads();
#pragma unroll
    for (int kk = 0; kk < 2; ++kk) {
      bf16x8 af[2], bfr[4];
      int k8 = kk * 4 + quad;
#pragma unroll
      for (int mi = 0; mi < 2; ++mi) {
        int row = wm + mi * 16 + l15;
        af[mi] = *(const bf16x8*)&As[row * 64 + ((k8 ^ (row & 7)) << 3)];
      }
#pragma unroll
      for (int ni = 0; ni < 4; ++ni) {
        int row = wn + ni * 16 + l15;
        bfr[ni] = *(const bf16x8*)&Bs[row * 64 + ((k8 ^ (row & 7)) << 3)];
      }
#pragma unroll
      for (int mi = 0; mi < 2; ++mi)
#pragma unroll
        for (int ni = 0; ni < 4; ++ni)
          acc[mi][ni] = __builtin_amdgcn_mfma_f32_16x16x32_bf16(af[mi], bfr[ni], acc[mi][ni], 0, 0, 0);
    }
    __syncthreads();
  }

  // epilogue: C/D layout col=lane&15, row=quad*4+reg (m89-verified)
#pragma unroll
  for (int mi = 0; mi < 2; ++mi) {
#pragma unroll
    for (int ni = 0; ni < 4; ++ni) {
      int col = wn + ni * 16 + l15;
      float bv = bias ? bias[col] : 0.f;
#pragma unroll
      for (int r = 0; r < 4; ++r) {
        int row = wm + mi * 16 + quad * 4 + r;
        int gr = rowBase + row;
        if (gr < M) {
          float v = acc[mi][ni][r] + bv;
          if (doRelu) v = fmaxf(v, 0.f);
          C[(size_t)gr * HD + col] = (bf16_t)v;
        }
      }
    }
  }
}

// ---- CSR build: pass1 computes per-edge slot via one atomic (also yields counts)
__global__ __launch_bounds__(256) void k_pos(const int* __restrict__ dst, int* __restrict__ cnt,
                                             int* __restrict__ pos, int E) {
  int e = blockIdx.x * 256 + threadIdx.x;
  if (e < E) pos[e] = atomicAdd(&cnt[dst[e]], 1);
}

// thread-serial chunk sums + one 1024-wide block scan
__global__ __launch_bounds__(1024) void k_scan(const int* __restrict__ cnt, int* __restrict__ off, int n) {
  __shared__ int s[1024];
  int t = threadIdx.x;
  const int CH = (n + 1023) / 1024;
  int base = t * CH;
  int sum = 0;
  for (int i = 0; i < CH; ++i) {
    int j = base + i;
    if (j < n) sum += cnt[j];
  }
  s[t] = sum;
  __syncthreads();
  for (int d = 1; d < 1024; d <<= 1) {
    int x = (t >= d) ? s[t - d] : 0;
    __syncthreads();
    s[t] += x;
    __syncthreads();
  }
  int excl = s[t] - sum;
  for (int i = 0; i < CH; ++i) {
    int j = base + i;
    if (j < n) {
      off[j] = excl;
      excl += cnt[j];
    }
  }
  if (t == 1023) off[n] = s[1023];
}

__global__ __launch_bounds__(256) void k_fill(const int* __restrict__ src, const int* __restrict__ dst,
                                              const int* __restrict__ off, const int* __restrict__ pos,
                                              int* __restrict__ ssrc, int E) {
  int e = blockIdx.x * 256 + threadIdx.x;
  if (e >= E) return;
  ssrc[off[dst[e]] + pos[e]] = src[e];
}

// ---- CSR mean-aggregate: agg[node] = mean over in-edges of h[src]
// 16 lanes/node x 8 feats, unroll-4 for load ILP, bf16 output.
__global__ __launch_bounds__(256) void k_aggregate(const bf16_t* __restrict__ h,
                                                   const int* __restrict__ ssrc,
                                                   const int* __restrict__ off,
                                                   bf16_t* __restrict__ agg, int n) {
  int node = blockIdx.x * 16 + (threadIdx.x >> 4);
  int lane = threadIdx.x & 15;
  if (node >= n) return;
  int b = off[node], e = off[node + 1];
  float acc[8];
#pragma unroll
  for (int j = 0; j < 8; ++j) acc[j] = 0.f;
  const bf16_t* hp = h + lane * 8;
  int i = b;
  for (; i + 4 <= e; i += 4) {
    int s0 = ssrc[i], s1 = ssrc[i + 1], s2 = ssrc[i + 2], s3 = ssrc[i + 3];
    bf16x8 v0 = *(const bf16x8*)(hp + (size_t)s0 * HD);
    bf16x8 v1 = *(const bf16x8*)(hp + (size_t)s1 * HD);
    bf16x8 v2 = *(const bf16x8*)(hp + (size_t)s2 * HD);
    bf16x8 v3 = *(const bf16x8*)(hp + (size_t)s3 * HD);
#pragma unroll
    for (int j = 0; j < 8; ++j)
      acc[j] += ((float)v0[j] + (float)v1[j]) + ((float)v2[j] + (float)v3[j]);
  }
  for (; i < e; ++i) {
    int s0 = ssrc[i];
    bf16x8 v0 = *(const bf16x8*)(hp + (size_t)s0 * HD);
#pragma unroll
    for (int j = 0; j < 8; ++j) acc[j] += (float)v0[j];
  }
  float inv = (e > b) ? 1.f / (float)(e - b) : 0.f;
  bf16x8 o;
#pragma unroll
  for (int j = 0; j < 8; ++j) o[j] = (bf16_t)(acc[j] * inv);
  *(bf16x8*)(agg + (size_t)node * HD + lane * 8) = o;
}

// ---- pool: segment-sum bf16 agg over sorted batch into p[64x128] + counts
__global__ __launch_bounds__(128) void k_pool(const bf16_t* __restrict__ agg, const int* __restrict__ batch,
                                              float* __restrict__ p, float* __restrict__ gcnt, int n) {
  int base = blockIdx.x * 256;
  if (base >= n) return;
  int t = threadIdx.x;
  int end = min(base + 256, n);
  float acc = 0.f;
  int curg = batch[base];
  int runStart = base;
  for (int i = base; i < end; ++i) {
    int g = batch[i];
    if (g != curg) {
      atomicAdd(&p[curg * HD + t], acc);
      if (t == 0) atomicAdd(&gcnt[curg], (float)(i - runStart));
      acc = 0.f; curg = g; runStart = i;
    }
    acc += (float)agg[(size_t)i * HD + t];
  }
  atomicAdd(&p[curg * HD + t], acc);
  if (t == 0) atomicAdd(&gcnt[curg], (float)(end - runStart));
}

// ---- head: z = (p/cnt) @ (w3*norm); out = mlp(z). One block per graph.
__global__ __launch_bounds__(128) void k_head(const float* __restrict__ p, const float* __restrict__ gcnt,
                                              const float* __restrict__ w3,
                                              const float* __restrict__ c1w, const float* __restrict__ c1b,
                                              const float* __restrict__ c2w, const float* __restrict__ c2b,
                                              const float* __restrict__ c3w, const float* __restrict__ c3b,
                                              float* __restrict__ out) {
  __shared__ float sa[128], sb[128];
  int g = blockIdx.x, t = threadIdx.x;
  float inv = 1.f / fmaxf(gcnt[g], 1.f);
  sa[t] = p[g * HD + t] * inv;
  __syncthreads();
  float z = 0.f;
  for (int k = 0; k < HD; ++k) z += sa[k] * w3[k * HD + t];
  z *= TP_NORM_F;
  out[128 + g * HD + t] = z;  // second output (z) region
  sb[t] = z;
  __syncthreads();
  float o1 = c1b[t];
  for (int k = 0; k < HD; ++k) o1 += sb[k] * c1w[k * HD + t];
  o1 = fmaxf(o1, 0.f);
  __syncthreads();
  sa[t] = o1;
  __syncthreads();
  float o2 = c2b[t];
  for (int k = 0; k < HD; ++k) o2 += sa[k] * c2w[k * HD + t];
  o2 = fmaxf(o2, 0.f);
  __syncthreads();
  sb[t] = o2;
  __syncthreads();
  if (t < 2) {
    float o = c3b[t];
    for (int k = 0; k < HD; ++k) o += sb[k] * c3w[k * 2 + t];
    out[g * 2 + t] = o;  // first output region
  }
}

extern "C" void kernel_launch(void* const* d_in, const int* in_sizes, int n_in,
                              void* d_out, int out_size, void* d_ws, size_t ws_size,
                              hipStream_t stream) {
  const float* x = (const float*)d_in[0];
  const int* eidx = (const int*)d_in[2];
  const int* src = eidx;
  const int* dst = eidx + N_EDGES;
  const int* batch = (const int*)d_in[3];
  const float* lin_w = (const float*)d_in[4];
  const float* lin_b = (const float*)d_in[5];
  const float* tp_w1 = (const float*)d_in[6];
  const float* tp_w2 = (const float*)d_in[7];
  const float* tp_w3 = (const float*)d_in[8];
  const float* c1w = (const float*)d_in[9];
  const float* c1b = (const float*)d_in[10];
  const float* c2w = (const float*)d_in[11];
  const float* c2b = (const float*)d_in[12];
  const float* c3w = (const float*)d_in[13];
  const float* c3b = (const float*)d_in[14];
  float* out = (float*)d_out;
  (void)in_sizes; (void)n_in; (void)out_size; (void)ws_size;

  uintptr_t wp = (uintptr_t)d_ws;
  auto alloc = [&](size_t bytes) -> void* {
    uintptr_t a = (wp + 255) & ~(uintptr_t)255;
    wp = a + bytes;
    return (void*)a;
  };
  bf16_t* WtL  = (bf16_t*)alloc(sizeof(bf16_t) * (size_t)HD * FIN);
  bf16_t* Wt1  = (bf16_t*)alloc(sizeof(bf16_t) * (size_t)HD * HD);
  bf16_t* Wt2  = (bf16_t*)alloc(sizeof(bf16_t) * (size_t)HD * HD);
  bf16_t* h    = (bf16_t*)alloc(sizeof(bf16_t) * (size_t)50048 * HD);
  bf16_t* agg  = (bf16_t*)alloc(sizeof(bf16_t) * (size_t)50048 * HD);
  int*    cnt  = (int*)alloc(sizeof(int) * N_NODES);
  int*    offs = (int*)alloc(sizeof(int) * (N_NODES + 1));
  int*    pos  = (int*)alloc(sizeof(int) * N_EDGES);
  int*    ssrc = (int*)alloc(sizeof(int) * N_EDGES);
  float*  pbuf = (float*)alloc(sizeof(float) * NG * HD);
  float*  gcnt = (float*)alloc(sizeof(float) * NG);

  hipMemsetAsync(cnt, 0, sizeof(int) * N_NODES, stream);
  hipMemsetAsync(pbuf, 0, sizeof(float) * NG * HD, stream);
  hipMemsetAsync(gcnt, 0, sizeof(float) * NG, stream);

  k_transpose_scale<<<(FIN * HD + 255) / 256, 256, 0, stream>>>(lin_w, WtL, FIN, 1.0f);
  k_transpose_scale<<<(HD * HD + 255) / 256, 256, 0, stream>>>(tp_w1, Wt1, HD, TP_NORM_F);
  k_transpose_scale<<<(HD * HD + 255) / 256, 256, 0, stream>>>(tp_w2, Wt2, HD, TP_NORM_F);

  k_pos<<<(N_EDGES + 255) / 256, 256, 0, stream>>>(dst, cnt, pos, N_EDGES);
  k_scan<<<1, 1024, 0, stream>>>(cnt, offs, N_NODES);
  k_fill<<<(N_EDGES + 255) / 256, 256, 0, stream>>>(src, dst, offs, pos, ssrc, N_EDGES);

  const int gblocks = (N_NODES + 63) / 64;   // 782
  const int ablocks = (N_NODES + 15) / 16;   // 3125

  // h0 = relu(x @ lin_w + b)
  k_gemm64<float><<<gblocks, 256, 0, stream>>>(x, WtL, lin_b, h, N_NODES, FIN, 1);

  // conv1: agg = mean_agg(h0[src]); h1 = relu(agg @ W1*norm)
  k_aggregate<<<ablocks, 256, 0, stream>>>(h, ssrc, offs, agg, N_NODES);
  k_gemm64<bf16_t><<<gblocks, 256, 0, stream>>>(agg, Wt1, nullptr, h, N_NODES, HD, 1);
  // conv2
  k_aggregate<<<ablocks, 256, 0, stream>>>(h, ssrc, offs, agg, N_NODES);
  k_gemm64<bf16_t><<<gblocks, 256, 0, stream>>>(agg, Wt2, nullptr, h, N_NODES, HD, 1);
  // conv3 aggregation only (W3 folded into head via linearity of segment-mean)
  k_aggregate<<<ablocks, 256, 0, stream>>>(h, ssrc, offs, agg, N_NODES);

  k_pool<<<(N_NODES + 255) / 256, 128, 0, stream>>>(agg, batch, pbuf, gcnt, N_NODES);
  k_head<<<NG, 128, 0, stream>>>(pbuf, gcnt, tp_w3, c1w, c1b, c2w, c2b, c3w, c3b, out);
}

// Round 3
// 782.207 us; speedup vs baseline: 1.2690x; 1.1227x over previous
//
#include <hip/hip_runtime.h>
#include <hip/hip_bf16.h>

typedef __bf16 bf16_t;
typedef bf16_t bf16x4 __attribute__((ext_vector_type(4)));
typedef bf16_t bf16x8 __attribute__((ext_vector_type(8)));
typedef float f32x4 __attribute__((ext_vector_type(4)));

static constexpr int N_NODES = 50000;
static constexpr int N_EDGES = 1600000;
static constexpr int FIN = 1280;
static constexpr int HD = 128;
static constexpr int NG = 64;
// 0.5/sqrt(pi)/sqrt(128)
static constexpr float TP_NORM_F = 0.0249338908f;

// ---- transpose + scale + cast: src [K x 128] f32 -> dst [128 x K] bf16
__global__ __launch_bounds__(256) void k_transpose_scale(const float* __restrict__ src,
                                                         bf16_t* __restrict__ dst,
                                                         int K, float scale) {
  int idx = blockIdx.x * 256 + threadIdx.x;
  if (idx >= K * HD) return;
  int k = idx >> 7, n = idx & 127;
  dst[n * K + k] = (bf16_t)(src[idx] * scale);
}

// ---- MFMA GEMM: C[M x 128] = act(A[M x K] @ Bt^T + bias)
// 32x128 block tile (1563 blocks -> ~6 blocks/CU for latency overlap),
// 4 waves each compute 32x32. BK=64, XOR-swizzled LDS.
// AT = float (cvt during staging) or bf16 (direct copy).
template <typename AT>
__global__ __launch_bounds__(256) void k_gemm32(const AT* __restrict__ A,
                                                const bf16_t* __restrict__ Bt,
                                                const float* __restrict__ bias,
                                                bf16_t* __restrict__ C,
                                                int M, int K, int doRelu) {
  __shared__ bf16_t As[32 * 64];
  __shared__ bf16_t Bs[128 * 64];
  const int t = threadIdx.x;
  const int wid = t >> 6;
  const int lane = t & 63;
  const int wn = wid * 32;   // 32-col slice per wave; all waves share all 32 rows
  const int l15 = lane & 15;
  const int quad = lane >> 4;
  const int rowBase = blockIdx.x * 32;

  f32x4 acc[2][2];
#pragma unroll
  for (int i = 0; i < 2; ++i)
#pragma unroll
    for (int j = 0; j < 2; ++j) {
      f32x4 z = {0.f, 0.f, 0.f, 0.f};
      acc[i][j] = z;
    }

  for (int k0 = 0; k0 < K; k0 += 64) {
    if constexpr (sizeof(AT) == 4) {
      // A: 32 rows x 64 f32 cols -> bf16; 512 float4 chunks / 256 thr = 2 each
#pragma unroll
      for (int i = 0; i < 2; ++i) {
        int idx = t + i * 256;
        int row = idx >> 4;   // 0..31
        int col4 = idx & 15;  // float4 units
        int gr = rowBase + row;
        float4 v = make_float4(0.f, 0.f, 0.f, 0.f);
        if (gr < M) v = *(const float4*)(A + (size_t)gr * K + k0 + col4 * 4);
        bf16x4 w;
        w[0] = (bf16_t)v.x; w[1] = (bf16_t)v.y; w[2] = (bf16_t)v.z; w[3] = (bf16_t)v.w;
        int c = col4 >> 1;
        int off = row * 64 + ((c ^ (row & 7)) << 3) + ((col4 & 1) << 2);
        *(bf16x4*)&As[off] = w;
      }
    } else {
      // A: 32 rows x 64 bf16 cols; 256 bf16x8 chunks / 256 thr = 1 each
      int row = t >> 3;  // 0..31
      int c = t & 7;     // 16B chunk
      int gr = rowBase + row;
      bf16x8 v = {};
      if (gr < M) v = *(const bf16x8*)(A + (size_t)gr * K + k0 + c * 8);
      int off = row * 64 + ((c ^ (row & 7)) << 3);
      *(bf16x8*)&As[off] = v;
    }
    // B: 128 rows x 64 bf16 cols, 1024 chunks / 256 thr = 4 each
#pragma unroll
    for (int i = 0; i < 4; ++i) {
      int idx = t + i * 256;
      int row = idx >> 3;  // 0..127
      int c = idx & 7;
      bf16x8 v = *(const bf16x8*)(Bt + (size_t)row * K + k0 + c * 8);
      int off = row * 64 + ((c ^ (row & 7)) << 3);
      *(bf16x8*)&Bs[off] = v;
    }
    __syncthreads();
#pragma unroll
    for (int kk = 0; kk < 2; ++kk) {
      bf16x8 af[2], bfr[2];
      int k8 = kk * 4 + quad;
#pragma unroll
      for (int mi = 0; mi < 2; ++mi) {
        int row = mi * 16 + l15;
        af[mi] = *(const bf16x8*)&As[row * 64 + ((k8 ^ (row & 7)) << 3)];
      }
#pragma unroll
      for (int ni = 0; ni < 2; ++ni) {
        int row = wn + ni * 16 + l15;
        bfr[ni] = *(const bf16x8*)&Bs[row * 64 + ((k8 ^ (row & 7)) << 3)];
      }
#pragma unroll
      for (int mi = 0; mi < 2; ++mi)
#pragma unroll
        for (int ni = 0; ni < 2; ++ni)
          acc[mi][ni] = __builtin_amdgcn_mfma_f32_16x16x32_bf16(af[mi], bfr[ni], acc[mi][ni], 0, 0, 0);
    }
    __syncthreads();
  }

  // epilogue: C/D layout col=lane&15, row=quad*4+reg (m89-verified)
#pragma unroll
  for (int mi = 0; mi < 2; ++mi) {
#pragma unroll
    for (int ni = 0; ni < 2; ++ni) {
      int col = wn + ni * 16 + l15;
      float bv = bias ? bias[col] : 0.f;
#pragma unroll
      for (int r = 0; r < 4; ++r) {
        int row = mi * 16 + quad * 4 + r;
        int gr = rowBase + row;
        if (gr < M) {
          float v = acc[mi][ni][r] + bv;
          if (doRelu) v = fmaxf(v, 0.f);
          C[(size_t)gr * HD + col] = (bf16_t)v;
        }
      }
    }
  }
}

// ---- CSR build: pass1 computes per-edge slot via one atomic (also yields counts)
__global__ __launch_bounds__(256) void k_pos(const int* __restrict__ dst, int* __restrict__ cnt,
                                             int* __restrict__ pos, int E) {
  int e = blockIdx.x * 256 + threadIdx.x;
  if (e < E) pos[e] = atomicAdd(&cnt[dst[e]], 1);
}

// hierarchical scan: (1) per-block sums, (2) scan block sums, (3) add-back
__global__ __launch_bounds__(256) void k_scan1(const int* __restrict__ cnt, int* __restrict__ bsum, int n) {
  __shared__ int s[256];
  int t = threadIdx.x;
  int i = blockIdx.x * 256 + t;
  s[t] = (i < n) ? cnt[i] : 0;
  __syncthreads();
  for (int d = 128; d > 0; d >>= 1) {
    if (t < d) s[t] += s[t + d];
    __syncthreads();
  }
  if (t == 0) bsum[blockIdx.x] = s[0];
}

__global__ __launch_bounds__(256) void k_scan2(int* __restrict__ bsum, int nb) {
  __shared__ int s[256];
  int t = threadIdx.x;
  int v = (t < nb) ? bsum[t] : 0;
  s[t] = v;
  __syncthreads();
  for (int d = 1; d < 256; d <<= 1) {
    int x = (t >= d) ? s[t - d] : 0;
    __syncthreads();
    s[t] += x;
    __syncthreads();
  }
  if (t < nb) bsum[t] = s[t] - v;  // exclusive
  if (t == 255) bsum[nb] = s[255]; // total
}

__global__ __launch_bounds__(256) void k_scan3(const int* __restrict__ cnt, const int* __restrict__ bsum,
                                               int* __restrict__ off, int n) {
  __shared__ int s[256];
  int t = threadIdx.x;
  int i = blockIdx.x * 256 + t;
  int v = (i < n) ? cnt[i] : 0;
  s[t] = v;
  __syncthreads();
  for (int d = 1; d < 256; d <<= 1) {
    int x = (t >= d) ? s[t - d] : 0;
    __syncthreads();
    s[t] += x;
    __syncthreads();
  }
  if (i < n) off[i] = bsum[blockIdx.x] + s[t] - v;
  if (i == n - 1) off[n] = bsum[blockIdx.x] + s[t];
}

__global__ __launch_bounds__(256) void k_fill(const int* __restrict__ src, const int* __restrict__ dst,
                                              const int* __restrict__ off, const int* __restrict__ pos,
                                              int* __restrict__ ssrc, int E) {
  int e = blockIdx.x * 256 + threadIdx.x;
  if (e >= E) return;
  ssrc[off[dst[e]] + pos[e]] = src[e];
}

// ---- CSR mean-aggregate, wave-per-node: 4 lane-groups x 16 lanes.
// Group g handles edges i+g; lane&15 holds feature slice of 8 bf16 (16B loads).
// 8 row-loads in flight per wave; zero intra-wave degree divergence.
__global__ __launch_bounds__(256) void k_aggregate(const bf16_t* __restrict__ h,
                                                   const int* __restrict__ ssrc,
                                                   const int* __restrict__ off,
                                                   bf16_t* __restrict__ agg, int n) {
  int node = blockIdx.x * 4 + (threadIdx.x >> 6);
  if (node >= n) return;
  int lane = threadIdx.x & 63;
  int g = lane >> 4;
  int fl = lane & 15;
  int b = off[node], e = off[node + 1];
  float acc[8];
#pragma unroll
  for (int j = 0; j < 8; ++j) acc[j] = 0.f;
  const bf16_t* hp = h + fl * 8;
  int i = b;
  for (; i + 8 <= e; i += 8) {
    int s0 = ssrc[i + g];
    int s1 = ssrc[i + 4 + g];
    bf16x8 v0 = *(const bf16x8*)(hp + (size_t)s0 * HD);
    bf16x8 v1 = *(const bf16x8*)(hp + (size_t)s1 * HD);
#pragma unroll
    for (int j = 0; j < 8; ++j) acc[j] += (float)v0[j] + (float)v1[j];
  }
  if (i + 4 <= e) {
    int s0 = ssrc[i + g];
    bf16x8 v0 = *(const bf16x8*)(hp + (size_t)s0 * HD);
#pragma unroll
    for (int j = 0; j < 8; ++j) acc[j] += (float)v0[j];
    i += 4;
  }
  if (i + g < e) {
    int s0 = ssrc[i + g];
    bf16x8 v0 = *(const bf16x8*)(hp + (size_t)s0 * HD);
#pragma unroll
    for (int j = 0; j < 8; ++j) acc[j] += (float)v0[j];
  }
  // reduce across the 4 lane-groups (lanes with equal lane&15 hold same slice)
#pragma unroll
  for (int j = 0; j < 8; ++j) {
    acc[j] += __shfl_xor(acc[j], 16);
    acc[j] += __shfl_xor(acc[j], 32);
  }
  if (g == 0) {
    float inv = (e > b) ? 1.f / (float)(e - b) : 0.f;
    bf16x8 o;
#pragma unroll
    for (int j = 0; j < 8; ++j) o[j] = (bf16_t)(acc[j] * inv);
    *(bf16x8*)(agg + (size_t)node * HD + fl * 8) = o;
  }
}

// ---- pool: segment-sum bf16 agg over sorted batch into p[64x128] + counts
__global__ __launch_bounds__(128) void k_pool(const bf16_t* __restrict__ agg, const int* __restrict__ batch,
                                              float* __restrict__ p, float* __restrict__ gcnt, int n) {
  int base = blockIdx.x * 256;
  if (base >= n) return;
  int t = threadIdx.x;
  int end = min(base + 256, n);
  float acc = 0.f;
  int curg = batch[base];
  int runStart = base;
  for (int i = base; i < end; ++i) {
    int g = batch[i];
    if (g != curg) {
      atomicAdd(&p[curg * HD + t], acc);
      if (t == 0) atomicAdd(&gcnt[curg], (float)(i - runStart));
      acc = 0.f; curg = g; runStart = i;
    }
    acc += (float)agg[(size_t)i * HD + t];
  }
  atomicAdd(&p[curg * HD + t], acc);
  if (t == 0) atomicAdd(&gcnt[curg], (float)(end - runStart));
}

// ---- head: z = (p/cnt) @ (w3*norm); out = mlp(z). One block per graph.
__global__ __launch_bounds__(128) void k_head(const float* __restrict__ p, const float* __restrict__ gcnt,
                                              const float* __restrict__ w3,
                                              const float* __restrict__ c1w, const float* __restrict__ c1b,
                                              const float* __restrict__ c2w, const float* __restrict__ c2b,
                                              const float* __restrict__ c3w, const float* __restrict__ c3b,
                                              float* __restrict__ out) {
  __shared__ float sa[128], sb[128];
  int g = blockIdx.x, t = threadIdx.x;
  float inv = 1.f / fmaxf(gcnt[g], 1.f);
  sa[t] = p[g * HD + t] * inv;
  __syncthreads();
  float z = 0.f;
  for (int k = 0; k < HD; ++k) z += sa[k] * w3[k * HD + t];
  z *= TP_NORM_F;
  out[128 + g * HD + t] = z;  // second output (z) region
  sb[t] = z;
  __syncthreads();
  float o1 = c1b[t];
  for (int k = 0; k < HD; ++k) o1 += sb[k] * c1w[k * HD + t];
  o1 = fmaxf(o1, 0.f);
  __syncthreads();
  sa[t] = o1;
  __syncthreads();
  float o2 = c2b[t];
  for (int k = 0; k < HD; ++k) o2 += sa[k] * c2w[k * HD + t];
  o2 = fmaxf(o2, 0.f);
  __syncthreads();
  sb[t] = o2;
  __syncthreads();
  if (t < 2) {
    float o = c3b[t];
    for (int k = 0; k < HD; ++k) o += sb[k] * c3w[k * 2 + t];
    out[g * 2 + t] = o;  // first output region
  }
}

extern "C" void kernel_launch(void* const* d_in, const int* in_sizes, int n_in,
                              void* d_out, int out_size, void* d_ws, size_t ws_size,
                              hipStream_t stream) {
  const float* x = (const float*)d_in[0];
  const int* eidx = (const int*)d_in[2];
  const int* src = eidx;
  const int* dst = eidx + N_EDGES;
  const int* batch = (const int*)d_in[3];
  const float* lin_w = (const float*)d_in[4];
  const float* lin_b = (const float*)d_in[5];
  const float* tp_w1 = (const float*)d_in[6];
  const float* tp_w2 = (const float*)d_in[7];
  const float* tp_w3 = (const float*)d_in[8];
  const float* c1w = (const float*)d_in[9];
  const float* c1b = (const float*)d_in[10];
  const float* c2w = (const float*)d_in[11];
  const float* c2b = (const float*)d_in[12];
  const float* c3w = (const float*)d_in[13];
  const float* c3b = (const float*)d_in[14];
  float* out = (float*)d_out;
  (void)in_sizes; (void)n_in; (void)out_size; (void)ws_size;

  uintptr_t wp = (uintptr_t)d_ws;
  auto alloc = [&](size_t bytes) -> void* {
    uintptr_t a = (wp + 255) & ~(uintptr_t)255;
    wp = a + bytes;
    return (void*)a;
  };
  bf16_t* WtL  = (bf16_t*)alloc(sizeof(bf16_t) * (size_t)HD * FIN);
  bf16_t* Wt1  = (bf16_t*)alloc(sizeof(bf16_t) * (size_t)HD * HD);
  bf16_t* Wt2  = (bf16_t*)alloc(sizeof(bf16_t) * (size_t)HD * HD);
  bf16_t* h    = (bf16_t*)alloc(sizeof(bf16_t) * (size_t)50048 * HD);
  bf16_t* agg  = (bf16_t*)alloc(sizeof(bf16_t) * (size_t)50048 * HD);
  int*    cnt  = (int*)alloc(sizeof(int) * N_NODES);
  int*    bsum = (int*)alloc(sizeof(int) * 256);
  int*    offs = (int*)alloc(sizeof(int) * (N_NODES + 1));
  int*    pos  = (int*)alloc(sizeof(int) * N_EDGES);
  int*    ssrc = (int*)alloc(sizeof(int) * N_EDGES);
  float*  pbuf = (float*)alloc(sizeof(float) * NG * HD);
  float*  gcnt = (float*)alloc(sizeof(float) * NG);

  hipMemsetAsync(cnt, 0, sizeof(int) * N_NODES, stream);
  hipMemsetAsync(pbuf, 0, sizeof(float) * NG * HD, stream);
  hipMemsetAsync(gcnt, 0, sizeof(float) * NG, stream);

  k_transpose_scale<<<(FIN * HD + 255) / 256, 256, 0, stream>>>(lin_w, WtL, FIN, 1.0f);
  k_transpose_scale<<<(HD * HD + 255) / 256, 256, 0, stream>>>(tp_w1, Wt1, HD, TP_NORM_F);
  k_transpose_scale<<<(HD * HD + 255) / 256, 256, 0, stream>>>(tp_w2, Wt2, HD, TP_NORM_F);

  const int nScanBlocks = (N_NODES + 255) / 256;  // 196
  k_pos<<<(N_EDGES + 255) / 256, 256, 0, stream>>>(dst, cnt, pos, N_EDGES);
  k_scan1<<<nScanBlocks, 256, 0, stream>>>(cnt, bsum, N_NODES);
  k_scan2<<<1, 256, 0, stream>>>(bsum, nScanBlocks);
  k_scan3<<<nScanBlocks, 256, 0, stream>>>(cnt, bsum, offs, N_NODES);
  k_fill<<<(N_EDGES + 255) / 256, 256, 0, stream>>>(src, dst, offs, pos, ssrc, N_EDGES);

  const int gblocks = (N_NODES + 31) / 32;   // 1563
  const int ablocks = (N_NODES + 3) / 4;     // 12500

  // h0 = relu(x @ lin_w + b)
  k_gemm32<float><<<gblocks, 256, 0, stream>>>(x, WtL, lin_b, h, N_NODES, FIN, 1);

  // conv1: agg = mean_agg(h0[src]); h1 = relu(agg @ W1*norm)
  k_aggregate<<<ablocks, 256, 0, stream>>>(h, ssrc, offs, agg, N_NODES);
  k_gemm32<bf16_t><<<gblocks, 256, 0, stream>>>(agg, Wt1, nullptr, h, N_NODES, HD, 1);
  // conv2
  k_aggregate<<<ablocks, 256, 0, stream>>>(h, ssrc, offs, agg, N_NODES);
  k_gemm32<bf16_t><<<gblocks, 256, 0, stream>>>(agg, Wt2, nullptr, h, N_NODES, HD, 1);
  // conv3 aggregation only (W3 folded into head via linearity of segment-mean)
  k_aggregate<<<ablocks, 256, 0, stream>>>(h, ssrc, offs, agg, N_NODES);

  k_pool<<<(N_NODES + 255) / 256, 128, 0, stream>>>(agg, batch, pbuf, gcnt, N_NODES);
  k_head<<<NG, 128, 0, stream>>>(pbuf, gcnt, tp_w3, c1w, c1b, c2w, c2b, c3w, c3b, out);
}